// Round 8
// baseline (147.394 us; speedup 1.0000x reference)
//
#include <hip/hip_runtime.h>
#include <math.h>

typedef unsigned short u16;
typedef unsigned long long u64;
typedef __bf16 bf16x8 __attribute__((ext_vector_type(8)));
typedef float f32x4 __attribute__((ext_vector_type(4)));

#define MAGIC 0xA5C3F00D9E1B7D42ULL

// ---------- helpers ----------
__device__ inline u16 bf16_rn(float x) {
    unsigned u = __float_as_uint(x);
    return (u16)((u + 0x7FFFu + ((u >> 16) & 1u)) >> 16);
}
__device__ inline uint2 pack4(u16 a, u16 b, u16 c, u16 d) {
    uint2 r;
    r.x = (unsigned)a | ((unsigned)b << 16);
    r.y = (unsigned)c | ((unsigned)d << 16);
    return r;
}
__device__ inline uint2 pack4f(float a, float b, float c, float d) {
    return pack4(bf16_rn(a), bf16_rn(b), bf16_rn(c), bf16_rn(d));
}
__device__ inline f32x4 mfma16(bf16x8 a, bf16x8 b, f32x4 c) {
    return __builtin_amdgcn_mfma_f32_16x16x32_bf16(a, b, c, 0, 0, 0);
}

// ---------- merged Node A + Node C: producer blocks 0..386 (R6 k_pre), consumer
// blocks 387..642 (R6 k_w2v, W2 load hoisted above the Upart wait).
// Handshake: per-producer MAGIC flag; all 643 blocks provably co-resident
// (256 thr, 18.3 KB LDS -> 8 blocks/CU -> capacity 2048), so spin cannot deadlock. ----------
__global__ __launch_bounds__(256) void k_prew2v(
    const float* __restrict__ x, const float* __restrict__ q, const float* __restrict__ p,
    const float* __restrict__ W1, const float* __restrict__ b1, const float* __restrict__ W2,
    u16* __restrict__ Ah, u16* __restrict__ W2h, u16* __restrict__ WTh,
    float* __restrict__ Upart, float* __restrict__ out, float* __restrict__ Vacc,
    float* __restrict__ H1g, float* __restrict__ D1g, u64* __restrict__ done) {
    __shared__ float T[64][65];
    __shared__ float hs[64], ds[64];
    __shared__ float red[4][64];
    __shared__ float zs[32];
    int b = blockIdx.x, t = threadIdx.x;

    if (b < 387) {
        // ================= producers: R6 k_pre verbatim =================
        if (b < 384) {
            int jc = b;                    // 0..383
            int k = (jc & 3) * 256 + t;    // 4 k-groups
            int j0 = (jc >> 2) * 32;       // 96 j-chunks
            if (t < 32) {
                int j = j0 + t;
                zs[t] = (j < 1024) ? x[j] : (j < 2048 ? q[j - 1024] : p[j - 2048]);
            }
            __syncthreads();
            float acc = 0.f;
            if (j0 < 1024) {
                // A-block rows: fuse bf16 cast with the GEMV read
#pragma unroll 8
                for (int j = 0; j < 32; ++j) {
                    float v = W1[(j0 + j) * 1024 + k];
                    Ah[(j0 + j) * 1024 + k] = bf16_rn(v);
                    acc += zs[j] * v;
                }
            } else {
#pragma unroll 8
                for (int j = 0; j < 32; ++j) acc += zs[j] * W1[(j0 + j) * 1024 + k];
            }
            Upart[(jc >> 2) * 1024 + k] = acc;  // 96 partials/k
        } else {
            int idx = ((b - 384) * 256 + t) * 4;  // 3072 floats: out[2048] + Vacc[1024]
            if (idx < 2048) *(float4*)(out + idx) = make_float4(0.f, 0.f, 0.f, 0.f);
            else *(float4*)(Vacc + idx - 2048) = make_float4(0.f, 0.f, 0.f, 0.f);
        }
        // release: all block stores drained (barrier implies vmcnt drain), then flag
        __syncthreads();
        if (t == 0) {
            __threadfence();
            __hip_atomic_store(&done[b], MAGIC, __ATOMIC_RELEASE, __HIP_MEMORY_SCOPE_AGENT);
        }
        return;
    }

    // ================= consumers: R6 k_w2v, W2 phase hoisted =================
    int c = b - 387;
    int k0 = (c >> 4) * 64, m0 = (c & 15) * 64;
    int rr = t >> 4, cc = (t & 15) * 4;
    // Phase A (independent of producers): W2 tile -> regs + T(LDS) + W2h cast
    float4 va[4];
#pragma unroll
    for (int j = 0; j < 4; ++j) {
        int r = rr + j * 16;
        float4 v = *(const float4*)(W2 + (k0 + r) * 1024 + m0 + cc);
        va[j] = v;
        T[r][cc + 0] = v.x; T[r][cc + 1] = v.y; T[r][cc + 2] = v.z; T[r][cc + 3] = v.w;
        *(uint2*)&W2h[(k0 + r) * 1024 + m0 + cc] = pack4f(v.x, v.y, v.z, v.w);
    }
    // Phase B: wait for all 387 producers
    for (;;) {
        int mine = 1;
        {
            u64 v0 = __hip_atomic_load(&done[t], __ATOMIC_RELAXED, __HIP_MEMORY_SCOPE_AGENT);
            mine = (v0 == MAGIC);
        }
        if (t + 256 < 387) {
            u64 v1 = __hip_atomic_load(&done[t + 256], __ATOMIC_RELAXED, __HIP_MEMORY_SCOPE_AGENT);
            mine = mine && (v1 == MAGIC);
        }
        if (__syncthreads_and(mine)) break;
        __builtin_amdgcn_s_sleep(8);
    }
    __threadfence();  // acquire: Upart + zeroed Vacc now visible
    // Phase C: reduce Upart (96 partials) -> h1/d1
    {
        int lk = t & 63, g = t >> 6;  // 4 groups x 24 chunks
        float u = 0.f;
#pragma unroll
        for (int c2 = 0; c2 < 24; ++c2) u += Upart[(g * 24 + c2) * 1024 + k0 + lk];
        red[g][lk] = u;
    }
    __syncthreads();
    if (t < 64) {
        float u = red[0][t] + red[1][t] + red[2][t] + red[3][t];
        float h = tanhf(u + b1[k0 + t]);
        hs[t] = h;
        ds[t] = 1.f - h * h;
        if (m0 == 0) { H1g[k0 + t] = h; D1g[k0 + t] = 1.f - h * h; }
    }
    __syncthreads();
    // Phase D: Vacc partials from registers (va) x hs
    float4 vp = make_float4(0.f, 0.f, 0.f, 0.f);
#pragma unroll
    for (int j = 0; j < 4; ++j) {
        float hk = hs[rr + j * 16];
        vp.x += hk * va[j].x; vp.y += hk * va[j].y; vp.z += hk * va[j].z; vp.w += hk * va[j].w;
    }
    vp.x += __shfl_xor(vp.x, 16); vp.y += __shfl_xor(vp.y, 16);
    vp.z += __shfl_xor(vp.z, 16); vp.w += __shfl_xor(vp.w, 16);
    vp.x += __shfl_xor(vp.x, 32); vp.y += __shfl_xor(vp.y, 32);
    vp.z += __shfl_xor(vp.z, 32); vp.w += __shfl_xor(vp.w, 32);
    if (((t & 63) >> 4) == 0) {
        atomicAdd(&Vacc[m0 + cc + 0], vp.x);
        atomicAdd(&Vacc[m0 + cc + 1], vp.y);
        atomicAdd(&Vacc[m0 + cc + 2], vp.z);
        atomicAdd(&Vacc[m0 + cc + 3], vp.w);
    }
    // Phase E: transpose+d1-scale -> WTh (T written in A, ds in C; both synced)
#pragma unroll
    for (int j = 0; j < 4; ++j) {
        int mrow = rr + j * 16;
        float f0 = T[cc + 0][mrow] * ds[cc + 0];
        float f1 = T[cc + 1][mrow] * ds[cc + 1];
        float f2 = T[cc + 2][mrow] * ds[cc + 2];
        float f3 = T[cc + 3][mrow] * ds[cc + 3];
        *(uint2*)&WTh[(m0 + mrow) * 1024 + k0 + cc] = pack4f(f0, f1, f2, f3);
    }
}

// ---------- dbuf BK=64 pure-bf16 MFMA GEMMs, 512 threads, split-K waves (R6-proven) ----------
#define LDK 68
__global__ __launch_bounds__(512) void k_gemm1(const u16* __restrict__ Ah,
                                               const u16* __restrict__ Bh,
                                               const float* __restrict__ Vacc,
                                               const float* __restrict__ b2,
                                               const float* __restrict__ W3,
                                               const float* __restrict__ W2,
                                               const float* __restrict__ H1,
                                               const float* __restrict__ D1,
                                               float* __restrict__ Avec,
                                               u16* __restrict__ Sh) {
    __shared__ u16 As[2][64 * LDK];
    __shared__ u16 Bs[2][64 * LDK];
    __shared__ float sv[1024];
    int tid = threadIdx.x;
    if (blockIdx.x == 16) {
        // ---- Avec GEMV tail, 16 blocks x 64 k ----
        int kbase = blockIdx.y * 64;
#pragma unroll
        for (int j = 0; j < 2; ++j) {
            int m = tid + j * 512;
            float h = tanhf(Vacc[m] + b2[m]);
            sv[m] = (1.f - h * h) * W3[m];
        }
        __syncthreads();
        int g = tid >> 3, sub = tid & 7;
        int k = kbase + g;
        const float* wrow = W2 + k * 1024 + sub * 128;
        const float* svp = sv + sub * 128;
        float acc = 0.f;
#pragma unroll 8
        for (int j = 0; j < 128; ++j) acc += wrow[j] * svp[j];
        acc += __shfl_xor(acc, 1);
        acc += __shfl_xor(acc, 2);
        acc += __shfl_xor(acc, 4);
        if (sub == 0) Avec[k] = -2.f * H1[k] * D1[k] * acc;
        return;
    }
    int lane = tid & 63, wv = tid >> 6;  // wv 0..7
    int kh = wv >> 2, wy = (wv >> 1) & 1, wx = wv & 1;
    int i0 = blockIdx.y * 64, m0 = blockIdx.x * 64;
    int srow = tid >> 3, sseg = (tid & 7) * 8;
    int ldso = srow * LDK + sseg;
    const u16* ap = Ah + (i0 + srow) * 1024 + sseg;
    const u16* bp = Bh + (m0 + srow) * 1024 + sseg;
    int tx = lane & 15, qy = lane >> 4;
    int koff = kh * 32 + qy * 8;
    int raA[2], rbB[2];
    raA[0] = (wy * 32 + tx) * LDK + koff;
    raA[1] = raA[0] + 16 * LDK;
    rbB[0] = (wx * 32 + tx) * LDK + koff;
    rbB[1] = rbB[0] + 16 * LDK;
    f32x4 acc[2][2];
#pragma unroll
    for (int a = 0; a < 2; ++a)
#pragma unroll
        for (int b = 0; b < 2; ++b) acc[a][b] = (f32x4){0.f, 0.f, 0.f, 0.f};

    uint4 pa1 = *(const uint4*)(ap + 64);   // depth-2 register prefetch
    uint4 pc1 = *(const uint4*)(bp + 64);
    *(uint4*)&As[0][ldso] = *(const uint4*)(ap);
    *(uint4*)&Bs[0][ldso] = *(const uint4*)(bp);

    for (int k0 = 0; k0 < 1024; k0 += 64) {
        int buf = (k0 >> 6) & 1;
        int kn2 = (k0 + 128) & 1023;  // wraps at tail; staged but never read
        uint4 pa2 = *(const uint4*)(ap + kn2);
        uint4 pc2 = *(const uint4*)(bp + kn2);
        __syncthreads();
        bf16x8 aH0 = *(const bf16x8*)&As[buf][raA[0]];
        bf16x8 aH1 = *(const bf16x8*)&As[buf][raA[1]];
        bf16x8 bH0 = *(const bf16x8*)&Bs[buf][rbB[0]];
        bf16x8 bH1 = *(const bf16x8*)&Bs[buf][rbB[1]];
        acc[0][0] = mfma16(aH0, bH0, acc[0][0]);
        acc[0][1] = mfma16(aH0, bH1, acc[0][1]);
        acc[1][0] = mfma16(aH1, bH0, acc[1][0]);
        acc[1][1] = mfma16(aH1, bH1, acc[1][1]);
        int nb = buf ^ 1;
        *(uint4*)&As[nb][ldso] = pa1;
        *(uint4*)&Bs[nb][ldso] = pc1;
        pa1 = pa2; pc1 = pc2;
    }
    // merge K-halves through LDS (reuse As as scratch)
    __syncthreads();
    f32x4* mrg = (f32x4*)&As[0][0];
    if (kh == 1) {
#pragma unroll
        for (int si = 0; si < 2; ++si)
#pragma unroll
            for (int sj = 0; sj < 2; ++sj)
                mrg[(((wy * 2 + wx) * 4 + si * 2 + sj) * 4 + qy) * 16 + tx] = acc[si][sj];
    }
    __syncthreads();
    if (kh == 0) {
#pragma unroll
        for (int si = 0; si < 2; ++si)
#pragma unroll
            for (int sj = 0; sj < 2; ++sj) {
                f32x4 o = mrg[(((wy * 2 + wx) * 4 + si * 2 + sj) * 4 + qy) * 16 + tx];
                acc[si][sj][0] += o[0]; acc[si][sj][1] += o[1];
                acc[si][sj][2] += o[2]; acc[si][sj][3] += o[3];
            }
#pragma unroll
        for (int sj = 0; sj < 2; ++sj) {
            int m = m0 + wx * 32 + sj * 16 + tx;
            float hv = tanhf(Vacc[m] + b2[m]);
            float d2 = 1.f - hv * hv;
            float cm = -2.f * hv * d2 * W3[m];  // Cvec inline
#pragma unroll
            for (int si = 0; si < 2; ++si) {
                int ib = i0 + wy * 32 + si * 16 + qy * 4;
#pragma unroll
                for (int r = 0; r < 4; ++r)
                    Sh[(ib + r) * 1024 + m] = bf16_rn(acc[si][sj][r] * cm);
            }
        }
    }
}

__global__ __launch_bounds__(512) void k_gemm2(const u16* __restrict__ Sh,
                                               const u16* __restrict__ W2h,
                                               const float* __restrict__ W1,
                                               const float* __restrict__ D1,
                                               const float* __restrict__ Avec,
                                               float* __restrict__ out) {
    __shared__ u16 As[2][64 * LDK];
    __shared__ u16 Bs[2][64 * LDK];
    int tid = threadIdx.x, lane = tid & 63, wv = tid >> 6;
    int kh = wv >> 2, wy = (wv >> 1) & 1, wx = wv & 1;
    int i0 = blockIdx.y * 64, k0g = blockIdx.x * 64;
    int srow = tid >> 3, sseg = (tid & 7) * 8;
    int ldso = srow * LDK + sseg;
    const u16* ap = Sh + (i0 + srow) * 1024 + sseg;
    const u16* bp = W2h + (k0g + srow) * 1024 + sseg;
    int tx = lane & 15, qy = lane >> 4;
    int koff = kh * 32 + qy * 8;
    int raA[2], rbB[2];
    raA[0] = (wy * 32 + tx) * LDK + koff;
    raA[1] = raA[0] + 16 * LDK;
    rbB[0] = (wx * 32 + tx) * LDK + koff;
    rbB[1] = rbB[0] + 16 * LDK;
    f32x4 acc[2][2];
#pragma unroll
    for (int a = 0; a < 2; ++a)
#pragma unroll
        for (int b = 0; b < 2; ++b) acc[a][b] = (f32x4){0.f, 0.f, 0.f, 0.f};

    uint4 pa1 = *(const uint4*)(ap + 64);
    uint4 pc1 = *(const uint4*)(bp + 64);
    *(uint4*)&As[0][ldso] = *(const uint4*)(ap);
    *(uint4*)&Bs[0][ldso] = *(const uint4*)(bp);

    for (int m0 = 0; m0 < 1024; m0 += 64) {
        int buf = (m0 >> 6) & 1;
        int mn2 = (m0 + 128) & 1023;
        uint4 pa2 = *(const uint4*)(ap + mn2);
        uint4 pc2 = *(const uint4*)(bp + mn2);
        __syncthreads();
        bf16x8 aH0 = *(const bf16x8*)&As[buf][raA[0]];
        bf16x8 aH1 = *(const bf16x8*)&As[buf][raA[1]];
        bf16x8 bH0 = *(const bf16x8*)&Bs[buf][rbB[0]];
        bf16x8 bH1 = *(const bf16x8*)&Bs[buf][rbB[1]];
        acc[0][0] = mfma16(aH0, bH0, acc[0][0]);
        acc[0][1] = mfma16(aH0, bH1, acc[0][1]);
        acc[1][0] = mfma16(aH1, bH0, acc[1][0]);
        acc[1][1] = mfma16(aH1, bH1, acc[1][1]);
        int nb = buf ^ 1;
        *(uint4*)&As[nb][ldso] = pa1;
        *(uint4*)&Bs[nb][ldso] = pc1;
        pa1 = pa2; pc1 = pc2;
    }
    // merge K-halves through LDS
    __syncthreads();
    f32x4* mrg = (f32x4*)&As[0][0];
    if (kh == 1) {
#pragma unroll
        for (int si = 0; si < 2; ++si)
#pragma unroll
            for (int sj = 0; sj < 2; ++sj)
                mrg[(((wy * 2 + wx) * 4 + si * 2 + sj) * 4 + qy) * 16 + tx] = acc[si][sj];
    }
    __syncthreads();
    if (kh == 0) {
#pragma unroll
        for (int si = 0; si < 2; ++si)
#pragma unroll
            for (int sj = 0; sj < 2; ++sj) {
                f32x4 o = mrg[(((wy * 2 + wx) * 4 + si * 2 + sj) * 4 + qy) * 16 + tx];
                acc[si][sj][0] += o[0]; acc[si][sj][1] += o[1];
                acc[si][sj][2] += o[2]; acc[si][sj][3] += o[3];
            }
        // fused epilogue: DR = Avec[k]*W1[i,k] + D1[k]*Wm[i,k]; dot with q/p rows of W1
        int kk[2];
        float d1v[2], avv[2];
#pragma unroll
        for (int sj = 0; sj < 2; ++sj) {
            kk[sj] = k0g + wx * 32 + sj * 16 + tx;
            d1v[sj] = D1[kk[sj]];
            avv[sj] = Avec[kk[sj]];
        }
#pragma unroll
        for (int si = 0; si < 2; ++si) {
            int ib = i0 + wy * 32 + si * 16 + qy * 4;
#pragma unroll
            for (int r = 0; r < 4; ++r) {
                int i = ib + r;
                float pq = 0.f, pp = 0.f;
#pragma unroll
                for (int sj = 0; sj < 2; ++sj) {
                    int k = kk[sj];
                    float dr = avv[sj] * W1[i * 1024 + k] + d1v[sj] * acc[si][sj][r];
                    pq += W1[(1024 + i) * 1024 + k] * dr;
                    pp += W1[(2048 + i) * 1024 + k] * dr;
                }
                for (int o = 1; o < 16; o <<= 1) {
                    pq += __shfl_xor(pq, o);
                    pp += __shfl_xor(pp, o);
                }
                if (tx == 0) {
                    atomicAdd(&out[i], pp);
                    atomicAdd(&out[1024 + i], -pq);
                }
            }
        }
    }
}

extern "C" void kernel_launch(void* const* d_in, const int* in_sizes, int n_in,
                              void* d_out, int out_size, void* d_ws, size_t ws_size,
                              hipStream_t stream) {
    const float* x = (const float*)d_in[0];
    const float* q = (const float*)d_in[1];
    const float* p = (const float*)d_in[2];
    const float* W1 = (const float*)d_in[3];
    const float* b1 = (const float*)d_in[4];
    const float* W2 = (const float*)d_in[5];
    const float* b2 = (const float*)d_in[6];
    const float* W3 = (const float*)d_in[7];
    float* out = (float*)d_out;
    float* ws = (float*)d_ws;
    float* H1 = ws, *D1 = ws + 1024, *Avec = ws + 2048, *Vacc = ws + 3072;
    float* Upart = ws + 4096;                       // 96*1024 floats
    u64* done = (u64*)(ws + 102400);                // 387 flags (3 KB)
    u16* u0 = (u16*)(ws + 131072);                  // bf16 arena
    u16* Ah = u0;
    u16* WTh = u0 + 1048576;
    u16* W2h = u0 + 2097152;
    u16* Sh = u0 + 3145728;

    k_prew2v<<<643, 256, 0, stream>>>(x, q, p, W1, b1, W2, Ah, W2h, WTh,
                                      Upart, out, Vacc, H1, D1, done);
    k_gemm1<<<dim3(17, 16), 512, 0, stream>>>(Ah, WTh, Vacc, b2, W3, W2, H1, D1, Avec, Sh);
    k_gemm2<<<dim3(16, 16), 512, 0, stream>>>(Sh, W2h, W1, D1, Avec, out);
}

// Round 9
// 146.650 us; speedup vs baseline: 1.0051x; 1.0051x over previous
//
#include <hip/hip_runtime.h>
#include <math.h>

typedef unsigned short u16;
typedef unsigned long long u64;
typedef __bf16 bf16x8 __attribute__((ext_vector_type(8)));
typedef float f32x4 __attribute__((ext_vector_type(4)));

#define MAGIC 0xA5C3F00D9E1B7D42ULL

// ---------- helpers ----------
__device__ inline u16 bf16_rn(float x) {
    unsigned u = __float_as_uint(x);
    return (u16)((u + 0x7FFFu + ((u >> 16) & 1u)) >> 16);
}
__device__ inline uint2 pack4(u16 a, u16 b, u16 c, u16 d) {
    uint2 r;
    r.x = (unsigned)a | ((unsigned)b << 16);
    r.y = (unsigned)c | ((unsigned)d << 16);
    return r;
}
__device__ inline uint2 pack4f(float a, float b, float c, float d) {
    return pack4(bf16_rn(a), bf16_rn(b), bf16_rn(c), bf16_rn(d));
}
__device__ inline f32x4 mfma16(bf16x8 a, bf16x8 b, f32x4 c) {
    return __builtin_amdgcn_mfma_f32_16x16x32_bf16(a, b, c, 0, 0, 0);
}

// ---------- merged Node A + Node C: producer blocks 0..386 (R6 k_pre), consumer
// blocks 387..642 (R6 k_w2v, W2 load hoisted above the Upart wait).
// Handshake v2: per-producer MAGIC flag, but ONLY WAVE 0 of each consumer polls
// (<=7 flags/lane + __all), s_sleep(32) between rounds -> poll traffic ~1 GB/s
// (v1 had 64K threads polling at s_sleep(8) = ~3.7 TB/s of atomic loads, which
// stalled the whole chip -- R8's 52.8us kernel). All 643 blocks co-resident
// (256 thr, 18.9 KB LDS -> 8 blocks/CU, capacity 2048), so spin cannot deadlock. ----------
__global__ __launch_bounds__(256) void k_prew2v(
    const float* __restrict__ x, const float* __restrict__ q, const float* __restrict__ p,
    const float* __restrict__ W1, const float* __restrict__ b1, const float* __restrict__ W2,
    u16* __restrict__ Ah, u16* __restrict__ W2h, u16* __restrict__ WTh,
    float* __restrict__ Upart, float* __restrict__ out, float* __restrict__ Vacc,
    float* __restrict__ H1g, float* __restrict__ D1g, u64* __restrict__ done) {
    __shared__ float T[64][65];
    __shared__ float hs[64], ds[64];
    __shared__ float red[4][64];
    __shared__ float zs[32];
    int b = blockIdx.x, t = threadIdx.x;

    if (b < 387) {
        // ================= producers: R6 k_pre verbatim =================
        if (b < 384) {
            int jc = b;                    // 0..383
            int k = (jc & 3) * 256 + t;    // 4 k-groups
            int j0 = (jc >> 2) * 32;       // 96 j-chunks
            if (t < 32) {
                int j = j0 + t;
                zs[t] = (j < 1024) ? x[j] : (j < 2048 ? q[j - 1024] : p[j - 2048]);
            }
            __syncthreads();
            float acc = 0.f;
            if (j0 < 1024) {
                // A-block rows: fuse bf16 cast with the GEMV read
#pragma unroll 8
                for (int j = 0; j < 32; ++j) {
                    float v = W1[(j0 + j) * 1024 + k];
                    Ah[(j0 + j) * 1024 + k] = bf16_rn(v);
                    acc += zs[j] * v;
                }
            } else {
#pragma unroll 8
                for (int j = 0; j < 32; ++j) acc += zs[j] * W1[(j0 + j) * 1024 + k];
            }
            Upart[(jc >> 2) * 1024 + k] = acc;  // 96 partials/k
        } else {
            int idx = ((b - 384) * 256 + t) * 4;  // 3072 floats: out[2048] + Vacc[1024]
            if (idx < 2048) *(float4*)(out + idx) = make_float4(0.f, 0.f, 0.f, 0.f);
            else *(float4*)(Vacc + idx - 2048) = make_float4(0.f, 0.f, 0.f, 0.f);
        }
        // release: all block stores drained, then flag
        __syncthreads();
        if (t == 0) {
            __threadfence();
            __hip_atomic_store(&done[b], MAGIC, __ATOMIC_RELEASE, __HIP_MEMORY_SCOPE_AGENT);
        }
        return;
    }

    // ================= consumers: R6 k_w2v, W2 phase hoisted =================
    int c = b - 387;
    int k0 = (c >> 4) * 64, m0 = (c & 15) * 64;
    int rr = t >> 4, cc = (t & 15) * 4;
    // Phase A (independent of producers): W2 tile -> regs + T(LDS) + W2h cast
    float4 va[4];
#pragma unroll
    for (int j = 0; j < 4; ++j) {
        int r = rr + j * 16;
        float4 v = *(const float4*)(W2 + (k0 + r) * 1024 + m0 + cc);
        va[j] = v;
        T[r][cc + 0] = v.x; T[r][cc + 1] = v.y; T[r][cc + 2] = v.z; T[r][cc + 3] = v.w;
        *(uint2*)&W2h[(k0 + r) * 1024 + m0 + cc] = pack4f(v.x, v.y, v.z, v.w);
    }
    // Phase B: wave 0 polls the 387 flags; waves 1-3 wait at the barrier
    if (t < 64) {
        for (;;) {
            int mine = 1;
            for (int j = t; j < 387; j += 64) {
                u64 v = __hip_atomic_load(&done[j], __ATOMIC_RELAXED, __HIP_MEMORY_SCOPE_AGENT);
                mine &= (int)(v == MAGIC);
            }
            if (__all(mine)) break;
            __builtin_amdgcn_s_sleep(32);
        }
    }
    __syncthreads();
    __threadfence();  // acquire: Upart + zeroed Vacc now visible
    // Phase C: reduce Upart (96 partials) -> h1/d1
    {
        int lk = t & 63, g = t >> 6;  // 4 groups x 24 chunks
        float u = 0.f;
#pragma unroll
        for (int c2 = 0; c2 < 24; ++c2) u += Upart[(g * 24 + c2) * 1024 + k0 + lk];
        red[g][lk] = u;
    }
    __syncthreads();
    if (t < 64) {
        float u = red[0][t] + red[1][t] + red[2][t] + red[3][t];
        float h = tanhf(u + b1[k0 + t]);
        hs[t] = h;
        ds[t] = 1.f - h * h;
        if (m0 == 0) { H1g[k0 + t] = h; D1g[k0 + t] = 1.f - h * h; }
    }
    __syncthreads();
    // Phase D: Vacc partials from registers (va) x hs
    float4 vp = make_float4(0.f, 0.f, 0.f, 0.f);
#pragma unroll
    for (int j = 0; j < 4; ++j) {
        float hk = hs[rr + j * 16];
        vp.x += hk * va[j].x; vp.y += hk * va[j].y; vp.z += hk * va[j].z; vp.w += hk * va[j].w;
    }
    vp.x += __shfl_xor(vp.x, 16); vp.y += __shfl_xor(vp.y, 16);
    vp.z += __shfl_xor(vp.z, 16); vp.w += __shfl_xor(vp.w, 16);
    vp.x += __shfl_xor(vp.x, 32); vp.y += __shfl_xor(vp.y, 32);
    vp.z += __shfl_xor(vp.z, 32); vp.w += __shfl_xor(vp.w, 32);
    if (((t & 63) >> 4) == 0) {
        atomicAdd(&Vacc[m0 + cc + 0], vp.x);
        atomicAdd(&Vacc[m0 + cc + 1], vp.y);
        atomicAdd(&Vacc[m0 + cc + 2], vp.z);
        atomicAdd(&Vacc[m0 + cc + 3], vp.w);
    }
    // Phase E: transpose+d1-scale -> WTh
#pragma unroll
    for (int j = 0; j < 4; ++j) {
        int mrow = rr + j * 16;
        float f0 = T[cc + 0][mrow] * ds[cc + 0];
        float f1 = T[cc + 1][mrow] * ds[cc + 1];
        float f2 = T[cc + 2][mrow] * ds[cc + 2];
        float f3 = T[cc + 3][mrow] * ds[cc + 3];
        *(uint2*)&WTh[(m0 + mrow) * 1024 + k0 + cc] = pack4f(f0, f1, f2, f3);
    }
}

// ---------- dbuf BK=64 pure-bf16 MFMA GEMMs, 512 threads, split-K waves (R6-proven) ----------
#define LDK 68
__global__ __launch_bounds__(512) void k_gemm1(const u16* __restrict__ Ah,
                                               const u16* __restrict__ Bh,
                                               const float* __restrict__ Vacc,
                                               const float* __restrict__ b2,
                                               const float* __restrict__ W3,
                                               const float* __restrict__ W2,
                                               const float* __restrict__ H1,
                                               const float* __restrict__ D1,
                                               float* __restrict__ Avec,
                                               u16* __restrict__ Sh) {
    __shared__ u16 As[2][64 * LDK];
    __shared__ u16 Bs[2][64 * LDK];
    __shared__ float sv[1024];
    int tid = threadIdx.x;
    if (blockIdx.x == 16) {
        // ---- Avec GEMV tail, 16 blocks x 64 k ----
        int kbase = blockIdx.y * 64;
#pragma unroll
        for (int j = 0; j < 2; ++j) {
            int m = tid + j * 512;
            float h = tanhf(Vacc[m] + b2[m]);
            sv[m] = (1.f - h * h) * W3[m];
        }
        __syncthreads();
        int g = tid >> 3, sub = tid & 7;
        int k = kbase + g;
        const float* wrow = W2 + k * 1024 + sub * 128;
        const float* svp = sv + sub * 128;
        float acc = 0.f;
#pragma unroll 8
        for (int j = 0; j < 128; ++j) acc += wrow[j] * svp[j];
        acc += __shfl_xor(acc, 1);
        acc += __shfl_xor(acc, 2);
        acc += __shfl_xor(acc, 4);
        if (sub == 0) Avec[k] = -2.f * H1[k] * D1[k] * acc;
        return;
    }
    int lane = tid & 63, wv = tid >> 6;  // wv 0..7
    int kh = wv >> 2, wy = (wv >> 1) & 1, wx = wv & 1;
    int i0 = blockIdx.y * 64, m0 = blockIdx.x * 64;
    int srow = tid >> 3, sseg = (tid & 7) * 8;
    int ldso = srow * LDK + sseg;
    const u16* ap = Ah + (i0 + srow) * 1024 + sseg;
    const u16* bp = Bh + (m0 + srow) * 1024 + sseg;
    int tx = lane & 15, qy = lane >> 4;
    int koff = kh * 32 + qy * 8;
    int raA[2], rbB[2];
    raA[0] = (wy * 32 + tx) * LDK + koff;
    raA[1] = raA[0] + 16 * LDK;
    rbB[0] = (wx * 32 + tx) * LDK + koff;
    rbB[1] = rbB[0] + 16 * LDK;
    f32x4 acc[2][2];
#pragma unroll
    for (int a = 0; a < 2; ++a)
#pragma unroll
        for (int b = 0; b < 2; ++b) acc[a][b] = (f32x4){0.f, 0.f, 0.f, 0.f};

    uint4 pa1 = *(const uint4*)(ap + 64);   // depth-2 register prefetch
    uint4 pc1 = *(const uint4*)(bp + 64);
    *(uint4*)&As[0][ldso] = *(const uint4*)(ap);
    *(uint4*)&Bs[0][ldso] = *(const uint4*)(bp);

    for (int k0 = 0; k0 < 1024; k0 += 64) {
        int buf = (k0 >> 6) & 1;
        int kn2 = (k0 + 128) & 1023;  // wraps at tail; staged but never read
        uint4 pa2 = *(const uint4*)(ap + kn2);
        uint4 pc2 = *(const uint4*)(bp + kn2);
        __syncthreads();
        bf16x8 aH0 = *(const bf16x8*)&As[buf][raA[0]];
        bf16x8 aH1 = *(const bf16x8*)&As[buf][raA[1]];
        bf16x8 bH0 = *(const bf16x8*)&Bs[buf][rbB[0]];
        bf16x8 bH1 = *(const bf16x8*)&Bs[buf][rbB[1]];
        acc[0][0] = mfma16(aH0, bH0, acc[0][0]);
        acc[0][1] = mfma16(aH0, bH1, acc[0][1]);
        acc[1][0] = mfma16(aH1, bH0, acc[1][0]);
        acc[1][1] = mfma16(aH1, bH1, acc[1][1]);
        int nb = buf ^ 1;
        *(uint4*)&As[nb][ldso] = pa1;
        *(uint4*)&Bs[nb][ldso] = pc1;
        pa1 = pa2; pc1 = pc2;
    }
    // merge K-halves through LDS (reuse As as scratch)
    __syncthreads();
    f32x4* mrg = (f32x4*)&As[0][0];
    if (kh == 1) {
#pragma unroll
        for (int si = 0; si < 2; ++si)
#pragma unroll
            for (int sj = 0; sj < 2; ++sj)
                mrg[(((wy * 2 + wx) * 4 + si * 2 + sj) * 4 + qy) * 16 + tx] = acc[si][sj];
    }
    __syncthreads();
    if (kh == 0) {
#pragma unroll
        for (int si = 0; si < 2; ++si)
#pragma unroll
            for (int sj = 0; sj < 2; ++sj) {
                f32x4 o = mrg[(((wy * 2 + wx) * 4 + si * 2 + sj) * 4 + qy) * 16 + tx];
                acc[si][sj][0] += o[0]; acc[si][sj][1] += o[1];
                acc[si][sj][2] += o[2]; acc[si][sj][3] += o[3];
            }
#pragma unroll
        for (int sj = 0; sj < 2; ++sj) {
            int m = m0 + wx * 32 + sj * 16 + tx;
            float hv = tanhf(Vacc[m] + b2[m]);
            float d2 = 1.f - hv * hv;
            float cm = -2.f * hv * d2 * W3[m];  // Cvec inline
#pragma unroll
            for (int si = 0; si < 2; ++si) {
                int ib = i0 + wy * 32 + si * 16 + qy * 4;
#pragma unroll
                for (int r = 0; r < 4; ++r)
                    Sh[(ib + r) * 1024 + m] = bf16_rn(acc[si][sj][r] * cm);
            }
        }
    }
}

__global__ __launch_bounds__(512) void k_gemm2(const u16* __restrict__ Sh,
                                               const u16* __restrict__ W2h,
                                               const float* __restrict__ W1,
                                               const float* __restrict__ D1,
                                               const float* __restrict__ Avec,
                                               float* __restrict__ out) {
    __shared__ u16 As[2][64 * LDK];
    __shared__ u16 Bs[2][64 * LDK];
    int tid = threadIdx.x, lane = tid & 63, wv = tid >> 6;
    int kh = wv >> 2, wy = (wv >> 1) & 1, wx = wv & 1;
    int i0 = blockIdx.y * 64, k0g = blockIdx.x * 64;
    int srow = tid >> 3, sseg = (tid & 7) * 8;
    int ldso = srow * LDK + sseg;
    const u16* ap = Sh + (i0 + srow) * 1024 + sseg;
    const u16* bp = W2h + (k0g + srow) * 1024 + sseg;
    int tx = lane & 15, qy = lane >> 4;
    int koff = kh * 32 + qy * 8;
    int raA[2], rbB[2];
    raA[0] = (wy * 32 + tx) * LDK + koff;
    raA[1] = raA[0] + 16 * LDK;
    rbB[0] = (wx * 32 + tx) * LDK + koff;
    rbB[1] = rbB[0] + 16 * LDK;
    f32x4 acc[2][2];
#pragma unroll
    for (int a = 0; a < 2; ++a)
#pragma unroll
        for (int b = 0; b < 2; ++b) acc[a][b] = (f32x4){0.f, 0.f, 0.f, 0.f};

    uint4 pa1 = *(const uint4*)(ap + 64);
    uint4 pc1 = *(const uint4*)(bp + 64);
    *(uint4*)&As[0][ldso] = *(const uint4*)(ap);
    *(uint4*)&Bs[0][ldso] = *(const uint4*)(bp);

    for (int m0 = 0; m0 < 1024; m0 += 64) {
        int buf = (m0 >> 6) & 1;
        int mn2 = (m0 + 128) & 1023;
        uint4 pa2 = *(const uint4*)(ap + mn2);
        uint4 pc2 = *(const uint4*)(bp + mn2);
        __syncthreads();
        bf16x8 aH0 = *(const bf16x8*)&As[buf][raA[0]];
        bf16x8 aH1 = *(const bf16x8*)&As[buf][raA[1]];
        bf16x8 bH0 = *(const bf16x8*)&Bs[buf][rbB[0]];
        bf16x8 bH1 = *(const bf16x8*)&Bs[buf][rbB[1]];
        acc[0][0] = mfma16(aH0, bH0, acc[0][0]);
        acc[0][1] = mfma16(aH0, bH1, acc[0][1]);
        acc[1][0] = mfma16(aH1, bH0, acc[1][0]);
        acc[1][1] = mfma16(aH1, bH1, acc[1][1]);
        int nb = buf ^ 1;
        *(uint4*)&As[nb][ldso] = pa1;
        *(uint4*)&Bs[nb][ldso] = pc1;
        pa1 = pa2; pc1 = pc2;
    }
    // merge K-halves through LDS
    __syncthreads();
    f32x4* mrg = (f32x4*)&As[0][0];
    if (kh == 1) {
#pragma unroll
        for (int si = 0; si < 2; ++si)
#pragma unroll
            for (int sj = 0; sj < 2; ++sj)
                mrg[(((wy * 2 + wx) * 4 + si * 2 + sj) * 4 + qy) * 16 + tx] = acc[si][sj];
    }
    __syncthreads();
    if (kh == 0) {
#pragma unroll
        for (int si = 0; si < 2; ++si)
#pragma unroll
            for (int sj = 0; sj < 2; ++sj) {
                f32x4 o = mrg[(((wy * 2 + wx) * 4 + si * 2 + sj) * 4 + qy) * 16 + tx];
                acc[si][sj][0] += o[0]; acc[si][sj][1] += o[1];
                acc[si][sj][2] += o[2]; acc[si][sj][3] += o[3];
            }
        // fused epilogue: DR = Avec[k]*W1[i,k] + D1[k]*Wm[i,k]; dot with q/p rows of W1
        int kk[2];
        float d1v[2], avv[2];
#pragma unroll
        for (int sj = 0; sj < 2; ++sj) {
            kk[sj] = k0g + wx * 32 + sj * 16 + tx;
            d1v[sj] = D1[kk[sj]];
            avv[sj] = Avec[kk[sj]];
        }
#pragma unroll
        for (int si = 0; si < 2; ++si) {
            int ib = i0 + wy * 32 + si * 16 + qy * 4;
#pragma unroll
            for (int r = 0; r < 4; ++r) {
                int i = ib + r;
                float pq = 0.f, pp = 0.f;
#pragma unroll
                for (int sj = 0; sj < 2; ++sj) {
                    int k = kk[sj];
                    float dr = avv[sj] * W1[i * 1024 + k] + d1v[sj] * acc[si][sj][r];
                    pq += W1[(1024 + i) * 1024 + k] * dr;
                    pp += W1[(2048 + i) * 1024 + k] * dr;
                }
                for (int o = 1; o < 16; o <<= 1) {
                    pq += __shfl_xor(pq, o);
                    pp += __shfl_xor(pp, o);
                }
                if (tx == 0) {
                    atomicAdd(&out[i], pp);
                    atomicAdd(&out[1024 + i], -pq);
                }
            }
        }
    }
}

extern "C" void kernel_launch(void* const* d_in, const int* in_sizes, int n_in,
                              void* d_out, int out_size, void* d_ws, size_t ws_size,
                              hipStream_t stream) {
    const float* x = (const float*)d_in[0];
    const float* q = (const float*)d_in[1];
    const float* p = (const float*)d_in[2];
    const float* W1 = (const float*)d_in[3];
    const float* b1 = (const float*)d_in[4];
    const float* W2 = (const float*)d_in[5];
    const float* b2 = (const float*)d_in[6];
    const float* W3 = (const float*)d_in[7];
    float* out = (float*)d_out;
    float* ws = (float*)d_ws;
    float* H1 = ws, *D1 = ws + 1024, *Avec = ws + 2048, *Vacc = ws + 3072;
    float* Upart = ws + 4096;                       // 96*1024 floats
    u64* done = (u64*)(ws + 102400);                // 387 flags (3 KB)
    u16* u0 = (u16*)(ws + 131072);                  // bf16 arena
    u16* Ah = u0;
    u16* WTh = u0 + 1048576;
    u16* W2h = u0 + 2097152;
    u16* Sh = u0 + 3145728;

    k_prew2v<<<643, 256, 0, stream>>>(x, q, p, W1, b1, W2, Ah, W2h, WTh,
                                      Upart, out, Vacc, H1, D1, done);
    k_gemm1<<<dim3(17, 16), 512, 0, stream>>>(Ah, WTh, Vacc, b2, W3, W2, H1, D1, Avec, Sh);
    k_gemm2<<<dim3(16, 16), 512, 0, stream>>>(Sh, W2h, W1, D1, Avec, out);
}

// Round 12
// 115.777 us; speedup vs baseline: 1.2731x; 1.2667x over previous
//
#include <hip/hip_runtime.h>
#include <math.h>

typedef unsigned short u16;
typedef __bf16 bf16x8 __attribute__((ext_vector_type(8)));
typedef float f32x4 __attribute__((ext_vector_type(4)));

// ---------- helpers ----------
__device__ inline u16 bf16_rn(float x) {
    unsigned u = __float_as_uint(x);
    return (u16)((u + 0x7FFFu + ((u >> 16) & 1u)) >> 16);
}
__device__ inline uint2 pack4(u16 a, u16 b, u16 c, u16 d) {
    uint2 r;
    r.x = (unsigned)a | ((unsigned)b << 16);
    r.y = (unsigned)c | ((unsigned)d << 16);
    return r;
}
__device__ inline uint2 pack4f(float a, float b, float c, float d) {
    return pack4(bf16_rn(a), bf16_rn(b), bf16_rn(c), bf16_rn(d));
}
__device__ inline f32x4 mfma16(bf16x8 a, bf16x8 b, f32x4 c) {
    return __builtin_amdgcn_mfma_f32_16x16x32_bf16(a, b, c, 0, 0, 0);
}

// ---------- Node A: u-partials, 32-j chunks (384 blocks -> 1.5 waves/SIMD)
//            A-block rows also emit bf16 cast; blocks 384..386 zero out/Vacc ----------
__global__ __launch_bounds__(256) void k_pre(const float* __restrict__ x,
                                             const float* __restrict__ q,
                                             const float* __restrict__ p,
                                             const float* __restrict__ W1,
                                             u16* __restrict__ Ah,
                                             float* __restrict__ Upart,
                                             float* __restrict__ out,
                                             float* __restrict__ Vacc) {
    int b = blockIdx.x, t = threadIdx.x;
    if (b < 384) {
        int jc = b;                    // 0..383
        int k = (jc & 3) * 256 + t;    // 4 k-groups
        int j0 = (jc >> 2) * 32;       // 96 j-chunks (32-aligned; x/q/p boundaries respected)
        __shared__ float zs[32];
        if (t < 32) {
            int j = j0 + t;
            zs[t] = (j < 1024) ? x[j] : (j < 2048 ? q[j - 1024] : p[j - 2048]);
        }
        __syncthreads();
        float acc = 0.f;
        if (j0 < 1024) {
            // A-block rows: fuse bf16 cast with the GEMV read (W1 A-block read once)
#pragma unroll 8
            for (int j = 0; j < 32; ++j) {
                float v = W1[(j0 + j) * 1024 + k];
                Ah[(j0 + j) * 1024 + k] = bf16_rn(v);
                acc += zs[j] * v;
            }
        } else {
#pragma unroll 8
            for (int j = 0; j < 32; ++j) acc += zs[j] * W1[(j0 + j) * 1024 + k];
        }
        Upart[(jc >> 2) * 1024 + k] = acc;  // plain store, no atomics (96 partials/k)
    } else {
        int idx = ((b - 384) * 256 + t) * 4;  // 3072 floats: out[2048] + Vacc[1024]
        if (idx < 2048) *(float4*)(out + idx) = make_float4(0.f, 0.f, 0.f, 0.f);
        else *(float4*)(Vacc + idx - 2048) = make_float4(0.f, 0.f, 0.f, 0.f);
    }
}

// ---------- Node C: 64k x 64m tiles, grid MUST be dim3(16,16) (body assumes
// k0 = blockIdx.y*64 < 1024 -- the R9-R11 crash was this body at grid y=32).
// reduce U (96 partials) -> h1/d1, split W2 -> W2h, transpose+d1-scale -> WTh,
// Vacc partials; m0==0 blocks publish H1/D1 ----------
__global__ __launch_bounds__(256) void k_w2v(const float* __restrict__ W2,
                                             const float* __restrict__ b1,
                                             const float* __restrict__ Upart,
                                             float* __restrict__ H1g, float* __restrict__ D1g,
                                             u16* __restrict__ W2h,
                                             u16* __restrict__ WTh,
                                             float* __restrict__ Vacc) {
    __shared__ float T[64][65];
    __shared__ float hs[64], ds[64];
    __shared__ float red[4][64];
    int k0 = blockIdx.y * 64, m0 = blockIdx.x * 64;
    int t = threadIdx.x;
    {
        int lk = t & 63, g = t >> 6;  // 4 groups x 24 chunks
        float u = 0.f;
#pragma unroll
        for (int c = 0; c < 24; ++c) u += Upart[(g * 24 + c) * 1024 + k0 + lk];
        red[g][lk] = u;
    }
    __syncthreads();
    if (t < 64) {
        float u = red[0][t] + red[1][t] + red[2][t] + red[3][t];
        float h = tanhf(u + b1[k0 + t]);
        hs[t] = h;
        ds[t] = 1.f - h * h;
        if (m0 == 0) { H1g[k0 + t] = h; D1g[k0 + t] = 1.f - h * h; }
    }
    __syncthreads();
    int rr = t >> 4, cc = (t & 15) * 4;
    float4 vp = make_float4(0.f, 0.f, 0.f, 0.f);
#pragma unroll
    for (int j = 0; j < 4; ++j) {
        int r = rr + j * 16;
        float4 v = *(const float4*)(W2 + (k0 + r) * 1024 + m0 + cc);
        T[r][cc + 0] = v.x; T[r][cc + 1] = v.y; T[r][cc + 2] = v.z; T[r][cc + 3] = v.w;
        *(uint2*)&W2h[(k0 + r) * 1024 + m0 + cc] = pack4f(v.x, v.y, v.z, v.w);
        float hk = hs[r];
        vp.x += hk * v.x; vp.y += hk * v.y; vp.z += hk * v.z; vp.w += hk * v.w;
    }
    vp.x += __shfl_xor(vp.x, 16); vp.y += __shfl_xor(vp.y, 16);
    vp.z += __shfl_xor(vp.z, 16); vp.w += __shfl_xor(vp.w, 16);
    vp.x += __shfl_xor(vp.x, 32); vp.y += __shfl_xor(vp.y, 32);
    vp.z += __shfl_xor(vp.z, 32); vp.w += __shfl_xor(vp.w, 32);
    if (((t & 63) >> 4) == 0) {
        atomicAdd(&Vacc[m0 + cc + 0], vp.x);
        atomicAdd(&Vacc[m0 + cc + 1], vp.y);
        atomicAdd(&Vacc[m0 + cc + 2], vp.z);
        atomicAdd(&Vacc[m0 + cc + 3], vp.w);
    }
    __syncthreads();
#pragma unroll
    for (int j = 0; j < 4; ++j) {
        int mrow = rr + j * 16;
        float f0 = T[cc + 0][mrow] * ds[cc + 0];
        float f1 = T[cc + 1][mrow] * ds[cc + 1];
        float f2 = T[cc + 2][mrow] * ds[cc + 2];
        float f3 = T[cc + 3][mrow] * ds[cc + 3];
        *(uint2*)&WTh[(m0 + mrow) * 1024 + k0 + cc] = pack4f(f0, f1, f2, f3);
    }
}

// ---------- dbuf BK=64 pure-bf16 MFMA GEMMs, 512 threads, split-K waves (R2-proven) ----------
#define LDK 68
__global__ __launch_bounds__(512) void k_gemm1(const u16* __restrict__ Ah,
                                               const u16* __restrict__ Bh,
                                               const float* __restrict__ Vacc,
                                               const float* __restrict__ b2,
                                               const float* __restrict__ W3,
                                               const float* __restrict__ W2,
                                               const float* __restrict__ H1,
                                               const float* __restrict__ D1,
                                               float* __restrict__ Avec,
                                               u16* __restrict__ Sh) {
    __shared__ u16 As[2][64 * LDK];
    __shared__ u16 Bs[2][64 * LDK];
    __shared__ float sv[1024];
    int tid = threadIdx.x;
    if (blockIdx.x == 16) {
        // ---- Avec GEMV tail, 16 blocks x 64 k ----
        int kbase = blockIdx.y * 64;
#pragma unroll
        for (int j = 0; j < 2; ++j) {
            int m = tid + j * 512;
            float h = tanhf(Vacc[m] + b2[m]);
            sv[m] = (1.f - h * h) * W3[m];
        }
        __syncthreads();
        int g = tid >> 3, sub = tid & 7;
        int k = kbase + g;
        const float* wrow = W2 + k * 1024 + sub * 128;
        const float* svp = sv + sub * 128;
        float acc = 0.f;
#pragma unroll 8
        for (int j = 0; j < 128; ++j) acc += wrow[j] * svp[j];
        acc += __shfl_xor(acc, 1);
        acc += __shfl_xor(acc, 2);
        acc += __shfl_xor(acc, 4);
        if (sub == 0) Avec[k] = -2.f * H1[k] * D1[k] * acc;
        return;
    }
    int lane = tid & 63, wv = tid >> 6;  // wv 0..7
    int kh = wv >> 2, wy = (wv >> 1) & 1, wx = wv & 1;
    int i0 = blockIdx.y * 64, m0 = blockIdx.x * 64;
    int srow = tid >> 3, sseg = (tid & 7) * 8;
    int ldso = srow * LDK + sseg;
    const u16* ap = Ah + (i0 + srow) * 1024 + sseg;
    const u16* bp = Bh + (m0 + srow) * 1024 + sseg;
    int tx = lane & 15, qy = lane >> 4;
    int koff = kh * 32 + qy * 8;
    int raA[2], rbB[2];
    raA[0] = (wy * 32 + tx) * LDK + koff;
    raA[1] = raA[0] + 16 * LDK;
    rbB[0] = (wx * 32 + tx) * LDK + koff;
    rbB[1] = rbB[0] + 16 * LDK;
    f32x4 acc[2][2];
#pragma unroll
    for (int a = 0; a < 2; ++a)
#pragma unroll
        for (int b = 0; b < 2; ++b) acc[a][b] = (f32x4){0.f, 0.f, 0.f, 0.f};

    uint4 pa1 = *(const uint4*)(ap + 64);   // depth-2 register prefetch
    uint4 pc1 = *(const uint4*)(bp + 64);
    *(uint4*)&As[0][ldso] = *(const uint4*)(ap);
    *(uint4*)&Bs[0][ldso] = *(const uint4*)(bp);

    for (int k0 = 0; k0 < 1024; k0 += 64) {
        int buf = (k0 >> 6) & 1;
        int kn2 = (k0 + 128) & 1023;  // wraps at tail; staged but never read
        uint4 pa2 = *(const uint4*)(ap + kn2);
        uint4 pc2 = *(const uint4*)(bp + kn2);
        __syncthreads();
        bf16x8 aH0 = *(const bf16x8*)&As[buf][raA[0]];
        bf16x8 aH1 = *(const bf16x8*)&As[buf][raA[1]];
        bf16x8 bH0 = *(const bf16x8*)&Bs[buf][rbB[0]];
        bf16x8 bH1 = *(const bf16x8*)&Bs[buf][rbB[1]];
        acc[0][0] = mfma16(aH0, bH0, acc[0][0]);
        acc[0][1] = mfma16(aH0, bH1, acc[0][1]);
        acc[1][0] = mfma16(aH1, bH0, acc[1][0]);
        acc[1][1] = mfma16(aH1, bH1, acc[1][1]);
        int nb = buf ^ 1;
        *(uint4*)&As[nb][ldso] = pa1;
        *(uint4*)&Bs[nb][ldso] = pc1;
        pa1 = pa2; pc1 = pc2;
    }
    // merge K-halves through LDS (reuse As as scratch)
    __syncthreads();
    f32x4* mrg = (f32x4*)&As[0][0];
    if (kh == 1) {
#pragma unroll
        for (int si = 0; si < 2; ++si)
#pragma unroll
            for (int sj = 0; sj < 2; ++sj)
                mrg[(((wy * 2 + wx) * 4 + si * 2 + sj) * 4 + qy) * 16 + tx] = acc[si][sj];
    }
    __syncthreads();
    if (kh == 0) {
#pragma unroll
        for (int si = 0; si < 2; ++si)
#pragma unroll
            for (int sj = 0; sj < 2; ++sj) {
                f32x4 o = mrg[(((wy * 2 + wx) * 4 + si * 2 + sj) * 4 + qy) * 16 + tx];
                acc[si][sj][0] += o[0]; acc[si][sj][1] += o[1];
                acc[si][sj][2] += o[2]; acc[si][sj][3] += o[3];
            }
#pragma unroll
        for (int sj = 0; sj < 2; ++sj) {
            int m = m0 + wx * 32 + sj * 16 + tx;
            float hv = tanhf(Vacc[m] + b2[m]);
            float d2 = 1.f - hv * hv;
            float cm = -2.f * hv * d2 * W3[m];  // Cvec inline
#pragma unroll
            for (int si = 0; si < 2; ++si) {
                int ib = i0 + wy * 32 + si * 16 + qy * 4;
#pragma unroll
                for (int r = 0; r < 4; ++r)
                    Sh[(ib + r) * 1024 + m] = bf16_rn(acc[si][sj][r] * cm);
            }
        }
    }
}

__global__ __launch_bounds__(512) void k_gemm2(const u16* __restrict__ Sh,
                                               const u16* __restrict__ W2h,
                                               const float* __restrict__ W1,
                                               const float* __restrict__ D1,
                                               const float* __restrict__ Avec,
                                               float* __restrict__ out) {
    __shared__ u16 As[2][64 * LDK];
    __shared__ u16 Bs[2][64 * LDK];
    int tid = threadIdx.x, lane = tid & 63, wv = tid >> 6;
    int kh = wv >> 2, wy = (wv >> 1) & 1, wx = wv & 1;
    int i0 = blockIdx.y * 64, k0g = blockIdx.x * 64;
    int srow = tid >> 3, sseg = (tid & 7) * 8;
    int ldso = srow * LDK + sseg;
    const u16* ap = Sh + (i0 + srow) * 1024 + sseg;
    const u16* bp = W2h + (k0g + srow) * 1024 + sseg;
    int tx = lane & 15, qy = lane >> 4;
    int koff = kh * 32 + qy * 8;
    int raA[2], rbB[2];
    raA[0] = (wy * 32 + tx) * LDK + koff;
    raA[1] = raA[0] + 16 * LDK;
    rbB[0] = (wx * 32 + tx) * LDK + koff;
    rbB[1] = rbB[0] + 16 * LDK;
    f32x4 acc[2][2];
#pragma unroll
    for (int a = 0; a < 2; ++a)
#pragma unroll
        for (int b = 0; b < 2; ++b) acc[a][b] = (f32x4){0.f, 0.f, 0.f, 0.f};

    uint4 pa1 = *(const uint4*)(ap + 64);
    uint4 pc1 = *(const uint4*)(bp + 64);
    *(uint4*)&As[0][ldso] = *(const uint4*)(ap);
    *(uint4*)&Bs[0][ldso] = *(const uint4*)(bp);

    for (int m0 = 0; m0 < 1024; m0 += 64) {
        int buf = (m0 >> 6) & 1;
        int mn2 = (m0 + 128) & 1023;
        uint4 pa2 = *(const uint4*)(ap + mn2);
        uint4 pc2 = *(const uint4*)(bp + mn2);
        __syncthreads();
        bf16x8 aH0 = *(const bf16x8*)&As[buf][raA[0]];
        bf16x8 aH1 = *(const bf16x8*)&As[buf][raA[1]];
        bf16x8 bH0 = *(const bf16x8*)&Bs[buf][rbB[0]];
        bf16x8 bH1 = *(const bf16x8*)&Bs[buf][rbB[1]];
        acc[0][0] = mfma16(aH0, bH0, acc[0][0]);
        acc[0][1] = mfma16(aH0, bH1, acc[0][1]);
        acc[1][0] = mfma16(aH1, bH0, acc[1][0]);
        acc[1][1] = mfma16(aH1, bH1, acc[1][1]);
        int nb = buf ^ 1;
        *(uint4*)&As[nb][ldso] = pa1;
        *(uint4*)&Bs[nb][ldso] = pc1;
        pa1 = pa2; pc1 = pc2;
    }
    // merge K-halves through LDS
    __syncthreads();
    f32x4* mrg = (f32x4*)&As[0][0];
    if (kh == 1) {
#pragma unroll
        for (int si = 0; si < 2; ++si)
#pragma unroll
            for (int sj = 0; sj < 2; ++sj)
                mrg[(((wy * 2 + wx) * 4 + si * 2 + sj) * 4 + qy) * 16 + tx] = acc[si][sj];
    }
    __syncthreads();
    if (kh == 0) {
#pragma unroll
        for (int si = 0; si < 2; ++si)
#pragma unroll
            for (int sj = 0; sj < 2; ++sj) {
                f32x4 o = mrg[(((wy * 2 + wx) * 4 + si * 2 + sj) * 4 + qy) * 16 + tx];
                acc[si][sj][0] += o[0]; acc[si][sj][1] += o[1];
                acc[si][sj][2] += o[2]; acc[si][sj][3] += o[3];
            }
        // fused epilogue: DR = Avec[k]*W1[i,k] + D1[k]*Wm[i,k]; dot with q/p rows of W1
        int kk[2];
        float d1v[2], avv[2];
#pragma unroll
        for (int sj = 0; sj < 2; ++sj) {
            kk[sj] = k0g + wx * 32 + sj * 16 + tx;
            d1v[sj] = D1[kk[sj]];
            avv[sj] = Avec[kk[sj]];
        }
#pragma unroll
        for (int si = 0; si < 2; ++si) {
            int ib = i0 + wy * 32 + si * 16 + qy * 4;
#pragma unroll
            for (int r = 0; r < 4; ++r) {
                int i = ib + r;
                float pq = 0.f, pp = 0.f;
#pragma unroll
                for (int sj = 0; sj < 2; ++sj) {
                    int k = kk[sj];
                    float dr = avv[sj] * W1[i * 1024 + k] + d1v[sj] * acc[si][sj][r];
                    pq += W1[(1024 + i) * 1024 + k] * dr;
                    pp += W1[(2048 + i) * 1024 + k] * dr;
                }
                for (int o = 1; o < 16; o <<= 1) {
                    pq += __shfl_xor(pq, o);
                    pp += __shfl_xor(pp, o);
                }
                if (tx == 0) {
                    atomicAdd(&out[i], pp);
                    atomicAdd(&out[1024 + i], -pq);
                }
            }
        }
    }
}

extern "C" void kernel_launch(void* const* d_in, const int* in_sizes, int n_in,
                              void* d_out, int out_size, void* d_ws, size_t ws_size,
                              hipStream_t stream) {
    const float* x = (const float*)d_in[0];
    const float* q = (const float*)d_in[1];
    const float* p = (const float*)d_in[2];
    const float* W1 = (const float*)d_in[3];
    const float* b1 = (const float*)d_in[4];
    const float* W2 = (const float*)d_in[5];
    const float* b2 = (const float*)d_in[6];
    const float* W3 = (const float*)d_in[7];
    float* out = (float*)d_out;
    float* ws = (float*)d_ws;
    float* H1 = ws, *D1 = ws + 1024, *Avec = ws + 2048, *Vacc = ws + 3072;
    float* Upart = ws + 4096;         // 96*1024 floats (384 KB)
    u16* u0 = (u16*)(ws + 131072);    // bf16 arena past enlarged Upart
    u16* Ah = u0;
    u16* WTh = u0 + 1048576;
    u16* W2h = u0 + 2097152;
    u16* Sh = u0 + 3145728;

    k_pre<<<387, 256, 0, stream>>>(x, q, p, W1, Ah, Upart, out, Vacc);
    k_w2v<<<dim3(16, 16), 256, 0, stream>>>(W2, b1, Upart, H1, D1, W2h, WTh, Vacc);
    k_gemm1<<<dim3(17, 16), 512, 0, stream>>>(Ah, WTh, Vacc, b2, W3, W2, H1, D1, Avec, Sh);
    k_gemm2<<<dim3(16, 16), 512, 0, stream>>>(Sh, W2h, W1, D1, Avec, out);
}